// Round 4
// baseline (549.397 us; speedup 1.0000x reference)
//
#include <hip/hip_runtime.h>
#include <hip/hip_bf16.h>
#include <math.h>

#define Gn 16000
#define Bn 4096
#define Ln 64
#define Sn 20000
#define GT 128     // genes per tile
#define NGT 125    // Gn/GT
#define NBY 64     // b blocks of 64

typedef __attribute__((ext_vector_type(8))) short bf16x8;   // 8 bf16 = 4 VGPRs
typedef __attribute__((ext_vector_type(4))) float f32x4;    // MFMA C/D

// ---------- device math helpers ----------

__device__ __forceinline__ float softplus_precise(float z) {
    return fmaxf(z, 0.0f) + log1pf(__expf(-fabsf(z)));
}

// accurate lgamma for z>0 (shift-8 Stirling), used only for the 100-entry table
__device__ __forceinline__ float lgamma_pos8(float z) {
    float p = z * (z + 1.f) * (z + 2.f) * (z + 3.f)
                * (z + 4.f) * (z + 5.f) * (z + 6.f) * (z + 7.f);
    float w = z + 8.f;
    return (w - 0.5f) * __logf(w) - w + 0.9189385332046727f
           + __fdividef(1.0f, 12.0f * w) - __logf(p);
}

__device__ __forceinline__ unsigned short f2bf(float f) {
    union { float f; unsigned int u; } v; v.f = f;
    unsigned int r = v.u + 0x7fff + ((v.u >> 16) & 1);   // RNE
    return (unsigned short)(r >> 16);
}

// async global -> LDS, 16B per lane; lds base wave-uniform (HW: base + lane*16)
__device__ __forceinline__ void load_lds16(const void* gsrc, void* lds) {
    __builtin_amdgcn_global_load_lds(
        (const __attribute__((address_space(1))) unsigned int*)gsrc,
        (__attribute__((address_space(3))) unsigned int*)lds,
        16, 0, 0);
}

__device__ __forceinline__ unsigned int pack4(int4 v) {
    return (unsigned int)(v.x & 255) | ((unsigned int)(v.y & 255) << 8)
         | ((unsigned int)(v.z & 255) << 16) | ((unsigned int)(v.w & 255) << 24);
}

// ---------- precompute kernels ----------

__global__ void prep_genes(const float* __restrict__ W,
                           const float* __restrict__ px_o,
                           const float* __restrict__ eta,
                           const float* __restrict__ beta,
                           unsigned short* __restrict__ rhB,
                           float4* __restrict__ gcon) {
    int idx = blockIdx.x * 256 + threadIdx.x;   // Gn*64 total, exact
    int g = idx >> 6;
    float bsp = softplus_precise(beta[g]);
    rhB[idx] = f2bf(bsp * softplus_precise(W[idx]));   // W row-major [G][L]
    if (idx < Gn) {
        float o = px_o[idx];
        float4 c;
        c.x = -softplus_precise(-o) - 1.0f;   // log_sigmoid(o) - 1
        c.y = -softplus_precise(o);           // log_sigmoid(-o)
        c.z = softplus_precise(eta[idx]);     // eps
        c.w = 0.f;
        gcon[idx] = c;
    }
}

__global__ void prep_spots(const float* __restrict__ V,
                           const int* __restrict__ ind_x,
                           unsigned short* __restrict__ vBg,
                           float* __restrict__ v64) {
    int idx = blockIdx.x * 256 + threadIdx.x;   // Bn*64 total, exact
    int b = idx >> 6, l = idx & 63;
    int s = ind_x[b];
    vBg[idx] = f2bf(softplus_precise(V[l * Sn + s]));
    if (idx < Bn) {
        int s2 = ind_x[idx];
        v64[idx] = softplus_precise(V[Ln * Sn + s2]);
    }
}

// prior: parallel, atomicAdd into out[Bn+1] (out pre-zeroed by memset)
__global__ void prior_kernel(const float* __restrict__ eta, float* __restrict__ out) {
    int idx = blockIdx.x * 256 + threadIdx.x;
    float s = 0.f;
    if (idx < Gn) {
        float e = eta[idx];
        s = 0.9189385332046727f + 0.5f * e * e;
    }
    #pragma unroll
    for (int off = 32; off; off >>= 1) s += __shfl_xor(s, off, 64);
    __shared__ float red[4];
    if ((threadIdx.x & 63) == 0) red[threadIdx.x >> 6] = s;
    __syncthreads();
    if (threadIdx.x == 0) atomicAdd(&out[Bn + 1], red[0] + red[1] + red[2] + red[3]);
}

// ---------- main kernel: one-shot 64b x 128g tile ----------
//
// term = lgamma(x+r) - lgamma(r) - lgamma(x+1) + x*lsp + r*lsn
//      ~= (s-0.5)ln s - (r-0.5)ln r + x*(lsp-1) + r*lsn - lfact[x],  s = r+x
//
// v5: 128-gene tiles -> 512B contiguous x-chunk per b-row (DRAM-friendly),
// x packed int32->u8 in-register during staging (LDS x = 8 KB), sB staged
// via global_load_lds with pre-swizzled source slots. LDS ~25 KB -> 6 blk/CU.
//
// Swizzle scheme (16B slots, 8 slots/row both tiles):
//   stored slot s0 at row holds source slot s0 ^ (row&7); readers XOR the same.

__global__ __launch_bounds__(256, 6) void main_kernel(
    const int*            __restrict__ x,
    const unsigned short* __restrict__ rhB,
    const unsigned short* __restrict__ vBg,
    const float*          __restrict__ v64,
    const float4*         __restrict__ gcon,
    float*                __restrict__ partial) {
    __shared__ __align__(16) unsigned int   sXw[64 * 32];    // 8 KB packed u8 [64][128]
    __shared__ __align__(16) unsigned short sB[GT * 64];     // 16 KB rh tile [128][64]
    __shared__ float lfact[100];
    __shared__ float pred[64];

    const int tid  = threadIdx.x;
    const int wave = tid >> 6, lane = tid & 63;
    const int quad = lane >> 4, ln = lane & 15;
    const int gt = blockIdx.x;         // grid.x = 125 (g-minor: vBg stays L2-hot)
    const int b0 = blockIdx.y * 64;
    const int g0 = gt * GT;

    // ---- stage rh tile: 4 gload_lds/wave, 8 rows each; source-slot XOR ----
    #pragma unroll
    for (int c = 0; c < 4; ++c) {
        int rowc = wave * 32 + c * 8 + (lane >> 3);
        int slot = (lane & 7) ^ (rowc & 7);
        load_lds16(&rhB[(size_t)(g0 + rowc) * 64 + slot * 8],
                   (char*)sB + (wave * 32 + c * 8) * 128);
    }

    // ---- stage x tile: 512B/row contiguous reads, pack to u8, linear b128 write ----
    // packed slot F covers row F>>3, slot F&7; source slot pre-XOR'd so the
    // LDS write is linear (conflict-free) and readers use slot ^ (row&7).
    #pragma unroll
    for (int k = 0; k < 2; ++k) {
        const int F   = wave * 128 + k * 64 + lane;   // 16B-slot index in [0,512)
        const int row = F >> 3;
        const int s   = (F & 7) ^ (row & 7);          // source slot
        const int* src = &x[(size_t)(b0 + row) * Gn + g0 + s * 16];
        int4 a = *(const int4*)(src + 0);
        int4 b = *(const int4*)(src + 4);
        int4 c = *(const int4*)(src + 8);
        int4 d = *(const int4*)(src + 12);
        uint4 P;
        P.x = pack4(a); P.y = pack4(b); P.z = pack4(c); P.w = pack4(d);
        *(uint4*)&sXw[F * 4] = P;
    }

    const int mrow = wave * 16 + ln;         // A-fragment m index (b row)
    const int xrow = wave * 16 + quad * 4;   // C rows for this lane (4 regs)

    // block-constant A fragments (v tile) + per-row v64 straight into registers
    bf16x8 av0 = *(const bf16x8*)&vBg[(b0 + mrow) * 64 + quad * 8];
    bf16x8 av1 = *(const bf16x8*)&vBg[(b0 + mrow) * 64 + 32 + quad * 8];
    float vvr[4];
    #pragma unroll
    for (int r = 0; r < 4; r++) vvr[r] = v64[b0 + xrow + r];

    if (tid < 100) lfact[tid] = lgamma_pos8((float)tid + 1.0f);

    __syncthreads();   // drains gload_lds (vmcnt) + ds_writes (lgkm)

    // MFMA: K=64 in two steps, 8 n-blocks of 16 genes
    f32x4 acc[8];
    #pragma unroll
    for (int nb = 0; nb < 8; nb++) acc[nb] = (f32x4){0.f, 0.f, 0.f, 0.f};
    #pragma unroll
    for (int kb = 0; kb < 2; kb++) {
        bf16x8 af = kb ? av1 : av0;
        #pragma unroll
        for (int nb = 0; nb < 8; nb++) {
            const int nbr = nb * 16 + ln;   // gene row in tile
            const int boff = nbr * 128 + ((kb * 64 + quad * 16) ^ ((nbr & 7) << 4));
            bf16x8 bfr = *(const bf16x8*)((const char*)sB + boff);
            acc[nb] = __builtin_amdgcn_mfma_f32_16x16x32_bf16(af, bfr, acc[nb], 0, 0, 0);
        }
    }

    // NB epilogue; x read as swizzled dwords (4-lane broadcast, <=2-way banks)
    const int sh = (ln & 3) * 8;
    float rowacc[4] = {0.f, 0.f, 0.f, 0.f};
    #pragma unroll
    for (int nb = 0; nb < 8; nb++) {
        const float4 cc = gcon[g0 + nb * 16 + ln];
        const float lsp1v = cc.x;
        const float lsnv  = cc.y;
        const float ev    = cc.z;
        #pragma unroll
        for (int r = 0; r < 4; r++) {
            const int row = xrow + r;
            const unsigned int w = sXw[row * 32 + ((nb ^ (row & 7)) << 2) + (ln >> 2)];
            const int   xi = (int)((w >> sh) & 255u);
            const float rr = fmaf(ev, vvr[r], acc[nb][r]);   // + eps*v64, fp32
            const float xf = (float)xi;
            const float s  = rr + xf;
            float tt = fmaf(s - 0.5f, __logf(s), -lfact[xi]);
            tt = fmaf(-(rr - 0.5f), __logf(rr), tt);
            tt = fmaf(xf, lsp1v, tt);
            tt = fmaf(rr, lsnv, tt);
            rowacc[r] += tt;
        }
    }

    // reduce over the 16 gene-lanes of each quad; one coalesced store per block
    #pragma unroll
    for (int r = 0; r < 4; r++) {
        float v = rowacc[r];
        v += __shfl_xor(v, 1, 64);
        v += __shfl_xor(v, 2, 64);
        v += __shfl_xor(v, 4, 64);
        v += __shfl_xor(v, 8, 64);
        if (ln == 0) pred[xrow + r] = v;
    }
    __syncthreads();
    if (tid < 64) partial[(size_t)gt * Bn + b0 + tid] = pred[tid];
}

// fold partial[NGT][4096] -> out[b] (negated). Direct store, no atomics.
__global__ __launch_bounds__(256) void reduce_kernel(const float* __restrict__ partial,
                                                     float* __restrict__ out) {
    int b = blockIdx.x * 256 + threadIdx.x;
    float s0 = 0.f, s1 = 0.f, s2 = 0.f, s3 = 0.f, s4 = 0.f;
    for (int i = 0; i < NGT; i += 5) {
        s0 += partial[(size_t)(i + 0) * Bn + b];
        s1 += partial[(size_t)(i + 1) * Bn + b];
        s2 += partial[(size_t)(i + 2) * Bn + b];
        s3 += partial[(size_t)(i + 3) * Bn + b];
        s4 += partial[(size_t)(i + 4) * Bn + b];
    }
    out[b] = -(s0 + s1 + s2 + s3 + s4);
}

// ---------- launch ----------

extern "C" void kernel_launch(void* const* d_in, const int* in_sizes, int n_in,
                              void* d_out, int out_size, void* d_ws, size_t ws_size,
                              hipStream_t stream) {
    const int*   x     = (const int*)d_in[0];
    const int*   ind_x = (const int*)d_in[2];
    const float* W     = (const float*)d_in[3];
    const float* px_o  = (const float*)d_in[4];
    const float* eta   = (const float*)d_in[5];
    const float* V     = (const float*)d_in[6];
    const float* beta  = (const float*)d_in[7];
    float* out = (float*)d_out;

    // ws layout (bytes, all 64B-aligned):
    char* wsb = (char*)d_ws;
    unsigned short* rhB  = (unsigned short*)(wsb);            // Gn*64*2   = 2,048,000
    unsigned short* vBg  = (unsigned short*)(wsb + 2048000);  // Bn*64*2   =   524,288
    float*          v64  = (float*)(wsb + 2572288);           // Bn*4      =    16,384
    float4*         gcon = (float4*)(wsb + 2588672);          // Gn*16     =   256,000
    float*          part = (float*)(wsb + 2844672);           // NGT*Bn*4  = 2,048,000

    // zero out[Bn] filler slot + prior accumulator (prior uses atomicAdd)
    hipMemsetAsync(d_out, 0, (Bn + 2) * sizeof(float), stream);

    prep_genes<<<(Gn * 64) / 256, 256, 0, stream>>>(W, px_o, eta, beta, rhB, gcon);
    prep_spots<<<(Bn * 64) / 256, 256, 0, stream>>>(V, ind_x, vBg, v64);
    prior_kernel<<<(Gn + 255) / 256, 256, 0, stream>>>(eta, out);

    dim3 grid(NGT, NBY);   // 125 x 64 = 8000 blocks
    main_kernel<<<grid, 256, 0, stream>>>(x, rhB, vBg, v64, gcon, part);

    reduce_kernel<<<Bn / 256, 256, 0, stream>>>(part, out);
}

// Round 5
// 401.179 us; speedup vs baseline: 1.3695x; 1.3695x over previous
//
#include <hip/hip_runtime.h>
#include <hip/hip_bf16.h>
#include <math.h>

#define Gn 16000
#define Bn 4096
#define Ln 64
#define Sn 20000
#define GT 128     // genes per tile
#define NGT 125    // Gn/GT
#define NBY 64     // b blocks of 64

typedef __attribute__((ext_vector_type(8))) short bf16x8;   // 8 bf16 = 4 VGPRs
typedef __attribute__((ext_vector_type(4))) float f32x4;    // MFMA C/D

// ---------- device math helpers ----------

__device__ __forceinline__ float softplus_precise(float z) {
    return fmaxf(z, 0.0f) + log1pf(__expf(-fabsf(z)));
}

// accurate lgamma for z>0 (shift-8 Stirling), used only for the 100-entry table
__device__ __forceinline__ float lgamma_pos8(float z) {
    float p = z * (z + 1.f) * (z + 2.f) * (z + 3.f)
                * (z + 4.f) * (z + 5.f) * (z + 6.f) * (z + 7.f);
    float w = z + 8.f;
    return (w - 0.5f) * __logf(w) - w + 0.9189385332046727f
           + __fdividef(1.0f, 12.0f * w) - __logf(p);
}

__device__ __forceinline__ unsigned short f2bf(float f) {
    union { float f; unsigned int u; } v; v.f = f;
    unsigned int r = v.u + 0x7fff + ((v.u >> 16) & 1);   // RNE
    return (unsigned short)(r >> 16);
}

// async global -> LDS, 16B per lane; lds base wave-uniform (HW: base + lane*16)
__device__ __forceinline__ void load_lds16(const void* gsrc, void* lds) {
    __builtin_amdgcn_global_load_lds(
        (const __attribute__((address_space(1))) unsigned int*)gsrc,
        (__attribute__((address_space(3))) unsigned int*)lds,
        16, 0, 0);
}

__device__ __forceinline__ unsigned int pack4(int4 v) {
    return (unsigned int)(v.x & 255) | ((unsigned int)(v.y & 255) << 8)
         | ((unsigned int)(v.z & 255) << 16) | ((unsigned int)(v.w & 255) << 24);
}

// ---------- precompute kernels ----------

__global__ void prep_genes(const float* __restrict__ W,
                           const float* __restrict__ px_o,
                           const float* __restrict__ eta,
                           const float* __restrict__ beta,
                           unsigned short* __restrict__ rhB,
                           float4* __restrict__ gcon) {
    int idx = blockIdx.x * 256 + threadIdx.x;   // Gn*64 total, exact
    int g = idx >> 6;
    float bsp = softplus_precise(beta[g]);
    rhB[idx] = f2bf(bsp * softplus_precise(W[idx]));   // W row-major [G][L]
    if (idx < Gn) {
        float o = px_o[idx];
        float4 c;
        c.x = -softplus_precise(-o) - 1.0f;   // log_sigmoid(o) - 1
        c.y = -softplus_precise(o);           // log_sigmoid(-o)
        c.z = softplus_precise(eta[idx]);     // eps
        c.w = 0.f;
        gcon[idx] = c;
    }
}

__global__ void prep_spots(const float* __restrict__ V,
                           const int* __restrict__ ind_x,
                           unsigned short* __restrict__ vBg,
                           float* __restrict__ v64) {
    int idx = blockIdx.x * 256 + threadIdx.x;   // Bn*64 total, exact
    int b = idx >> 6, l = idx & 63;
    int s = ind_x[b];
    vBg[idx] = f2bf(softplus_precise(V[l * Sn + s]));
    if (idx < Bn) {
        int s2 = ind_x[idx];
        v64[idx] = softplus_precise(V[Ln * Sn + s2]);
    }
}

// prior: parallel, atomicAdd into out[Bn+1] (out pre-zeroed by memset)
__global__ void prior_kernel(const float* __restrict__ eta, float* __restrict__ out) {
    int idx = blockIdx.x * 256 + threadIdx.x;
    float s = 0.f;
    if (idx < Gn) {
        float e = eta[idx];
        s = 0.9189385332046727f + 0.5f * e * e;
    }
    #pragma unroll
    for (int off = 32; off; off >>= 1) s += __shfl_xor(s, off, 64);
    __shared__ float red[4];
    if ((threadIdx.x & 63) == 0) red[threadIdx.x >> 6] = s;
    __syncthreads();
    if (threadIdx.x == 0) atomicAdd(&out[Bn + 1], red[0] + red[1] + red[2] + red[3]);
}

// ---------- main kernel: one-shot 64b x 128g tile ----------
//
// term = lgamma(x+r) - lgamma(r) - lgamma(x+1) + x*lsp + r*lsn
//      ~= (s-0.5)ln s - (r-0.5)ln r + x*(lsp-1) + r*lsn - lfact[x],  s = r+x
//
// v6 (vs v5): fixed the scratch-spill regression —
//   * __launch_bounds__(256, 4): 128-VGPR cap; occupancy stays LDS-bound
//     at 6 blk/CU, so nothing lost, spills gone.
//   * per-nb fused MFMA+epilogue: live accumulator = ONE f32x4 (was 8),
//     register pressure now independent of tile width.
//
// Swizzle scheme (16B slots, 8 slots/row both tiles):
//   stored slot t at row holds source slot t ^ (row&7); readers XOR the same.

__global__ __launch_bounds__(256, 4) void main_kernel(
    const int*            __restrict__ x,
    const unsigned short* __restrict__ rhB,
    const unsigned short* __restrict__ vBg,
    const float*          __restrict__ v64,
    const float4*         __restrict__ gcon,
    float*                __restrict__ partial) {
    __shared__ __align__(16) unsigned int   sXw[64 * 32];    // 8 KB packed u8 [64][128]
    __shared__ __align__(16) unsigned short sB[GT * 64];     // 16 KB rh tile [128][64]
    __shared__ float lfact[100];
    __shared__ float pred[64];

    const int tid  = threadIdx.x;
    const int wave = tid >> 6, lane = tid & 63;
    const int quad = lane >> 4, ln = lane & 15;
    const int gt = blockIdx.x;         // grid.x = 125
    const int b0 = blockIdx.y * 64;
    const int g0 = gt * GT;

    // ---- stage rh tile: 4 gload_lds/wave, 8 rows each; source-slot XOR ----
    #pragma unroll
    for (int c = 0; c < 4; ++c) {
        int rowc = wave * 32 + c * 8 + (lane >> 3);
        int slot = (lane & 7) ^ (rowc & 7);
        load_lds16(&rhB[(size_t)(g0 + rowc) * 64 + slot * 8],
                   (char*)sB + (wave * 32 + c * 8) * 128);
    }

    // ---- stage x tile: 512B/row contiguous reads, pack to u8, linear b128 write ----
    // packed slot F covers row F>>3, slot F&7; source slot pre-XOR'd so the
    // LDS write is linear (conflict-free) and readers use slot ^ (row&7).
    #pragma unroll
    for (int k = 0; k < 2; ++k) {
        const int F   = wave * 128 + k * 64 + lane;   // 16B-slot index in [0,512)
        const int row = F >> 3;
        const int s   = (F & 7) ^ (row & 7);          // source slot
        const int* src = &x[(size_t)(b0 + row) * Gn + g0 + s * 16];
        int4 a = *(const int4*)(src + 0);
        int4 b = *(const int4*)(src + 4);
        int4 c = *(const int4*)(src + 8);
        int4 d = *(const int4*)(src + 12);
        uint4 P;
        P.x = pack4(a); P.y = pack4(b); P.z = pack4(c); P.w = pack4(d);
        *(uint4*)&sXw[F * 4] = P;
    }

    const int mrow = wave * 16 + ln;         // A-fragment m index (b row)
    const int xrow = wave * 16 + quad * 4;   // C rows for this lane (4 regs)

    // block-constant A fragments (v tile) + per-row v64 straight into registers
    bf16x8 av0 = *(const bf16x8*)&vBg[(b0 + mrow) * 64 + quad * 8];
    bf16x8 av1 = *(const bf16x8*)&vBg[(b0 + mrow) * 64 + 32 + quad * 8];
    float vvr[4];
    #pragma unroll
    for (int r = 0; r < 4; r++) vvr[r] = v64[b0 + xrow + r];

    if (tid < 100) lfact[tid] = lgamma_pos8((float)tid + 1.0f);

    __syncthreads();   // drains gload_lds (vmcnt) + ds_writes (lgkm)

    // fused MFMA + NB epilogue per 16-gene n-block: live acc = one f32x4
    const int sh = (ln & 3) * 8;
    float rowacc[4] = {0.f, 0.f, 0.f, 0.f};
    #pragma unroll
    for (int nb = 0; nb < 8; nb++) {
        const int nbr = nb * 16 + ln;   // gene row in tile
        const int rb  = nbr * 128;
        bf16x8 bf0 = *(const bf16x8*)((const char*)sB + rb + ((quad * 16) ^ ((nbr & 7) << 4)));
        bf16x8 bf1 = *(const bf16x8*)((const char*)sB + rb + ((64 + quad * 16) ^ ((nbr & 7) << 4)));
        f32x4 a = (f32x4){0.f, 0.f, 0.f, 0.f};
        a = __builtin_amdgcn_mfma_f32_16x16x32_bf16(av0, bf0, a, 0, 0, 0);
        a = __builtin_amdgcn_mfma_f32_16x16x32_bf16(av1, bf1, a, 0, 0, 0);

        const float4 cc = gcon[g0 + nb * 16 + ln];
        const float lsp1v = cc.x;
        const float lsnv  = cc.y;
        const float ev    = cc.z;
        #pragma unroll
        for (int r = 0; r < 4; r++) {
            const int row = xrow + r;
            const unsigned int w = sXw[row * 32 + ((nb ^ (row & 7)) << 2) + (ln >> 2)];
            const int   xi = (int)((w >> sh) & 255u);
            const float rr = fmaf(ev, vvr[r], a[r]);   // + eps*v64, fp32
            const float xf = (float)xi;
            const float s  = rr + xf;
            float tt = fmaf(s - 0.5f, __logf(s), -lfact[xi]);
            tt = fmaf(-(rr - 0.5f), __logf(rr), tt);
            tt = fmaf(xf, lsp1v, tt);
            tt = fmaf(rr, lsnv, tt);
            rowacc[r] += tt;
        }
    }

    // reduce over the 16 gene-lanes of each quad; one coalesced store per block
    #pragma unroll
    for (int r = 0; r < 4; r++) {
        float v = rowacc[r];
        v += __shfl_xor(v, 1, 64);
        v += __shfl_xor(v, 2, 64);
        v += __shfl_xor(v, 4, 64);
        v += __shfl_xor(v, 8, 64);
        if (ln == 0) pred[xrow + r] = v;
    }
    __syncthreads();
    if (tid < 64) partial[(size_t)gt * Bn + b0 + tid] = pred[tid];
}

// fold partial[NGT][4096] -> out[b] (negated). Direct store, no atomics.
__global__ __launch_bounds__(256) void reduce_kernel(const float* __restrict__ partial,
                                                     float* __restrict__ out) {
    int b = blockIdx.x * 256 + threadIdx.x;
    float s0 = 0.f, s1 = 0.f, s2 = 0.f, s3 = 0.f, s4 = 0.f;
    for (int i = 0; i < NGT; i += 5) {
        s0 += partial[(size_t)(i + 0) * Bn + b];
        s1 += partial[(size_t)(i + 1) * Bn + b];
        s2 += partial[(size_t)(i + 2) * Bn + b];
        s3 += partial[(size_t)(i + 3) * Bn + b];
        s4 += partial[(size_t)(i + 4) * Bn + b];
    }
    out[b] = -(s0 + s1 + s2 + s3 + s4);
}

// ---------- launch ----------

extern "C" void kernel_launch(void* const* d_in, const int* in_sizes, int n_in,
                              void* d_out, int out_size, void* d_ws, size_t ws_size,
                              hipStream_t stream) {
    const int*   x     = (const int*)d_in[0];
    const int*   ind_x = (const int*)d_in[2];
    const float* W     = (const float*)d_in[3];
    const float* px_o  = (const float*)d_in[4];
    const float* eta   = (const float*)d_in[5];
    const float* V     = (const float*)d_in[6];
    const float* beta  = (const float*)d_in[7];
    float* out = (float*)d_out;

    // ws layout (bytes, all 64B-aligned):
    char* wsb = (char*)d_ws;
    unsigned short* rhB  = (unsigned short*)(wsb);            // Gn*64*2   = 2,048,000
    unsigned short* vBg  = (unsigned short*)(wsb + 2048000);  // Bn*64*2   =   524,288
    float*          v64  = (float*)(wsb + 2572288);           // Bn*4      =    16,384
    float4*         gcon = (float4*)(wsb + 2588672);          // Gn*16     =   256,000
    float*          part = (float*)(wsb + 2844672);           // NGT*Bn*4  = 2,048,000

    // zero out[Bn] filler slot + prior accumulator (prior uses atomicAdd)
    hipMemsetAsync(d_out, 0, (Bn + 2) * sizeof(float), stream);

    prep_genes<<<(Gn * 64) / 256, 256, 0, stream>>>(W, px_o, eta, beta, rhB, gcon);
    prep_spots<<<(Bn * 64) / 256, 256, 0, stream>>>(V, ind_x, vBg, v64);
    prior_kernel<<<(Gn + 255) / 256, 256, 0, stream>>>(eta, out);

    dim3 grid(NGT, NBY);   // 125 x 64 = 8000 blocks
    main_kernel<<<grid, 256, 0, stream>>>(x, rhB, vBg, v64, gcon, part);

    reduce_kernel<<<Bn / 256, 256, 0, stream>>>(part, out);
}